// Round 23
// baseline (59.651 us; speedup 1.0000x reference)
//
#include <hip/hip_runtime.h>
#include <math.h>

typedef _Float16 half8 __attribute__((ext_vector_type(8)));
typedef _Float16 half4v __attribute__((ext_vector_type(4)));
typedef float    f32x4 __attribute__((ext_vector_type(4)));

// ---------------- output offsets (floats) ----------------
#define O_Q     0
#define O_LOSS  2097152
#define O_IDX   2097153
#define O_PERP  2129921
#define O_NECS  2129922
#define O_EMAW  2130946
#define O_W     2196482

// ---------------- workspace offsets (4-byte units) ----------------
#define W_WBF    0          // 65536 fl (=131072 halfs): B-fragments [64ct][4j][64l][8e]
#define W_SW2    65536      // 1024  wsq  (fl32 of fp64 sum)
#define W_CNT    132096     // 1024  counts
#define W_DW     133120     // 65536 dw
#define W_LOSS   198656     // 1     loss
#define W_ZN     66561      // floats to zero starting at W_CNT

#define F16_MIN_NORM 6.103515625e-05f   // 2^-14

// =====================================================================
// kernel 0 (prep, grid 256): wbf + wsq + zeroing (r21-verified)
// =====================================================================
__global__ __launch_bounds__(256)
void k_prep(const float* __restrict__ w,
            _Float16* __restrict__ wbf, float* __restrict__ wsq,
            float* __restrict__ zbase) {
    __shared__ float sh[64][65];
    int tid = threadIdx.x, blk = blockIdx.x;

    for (int z = blk * 256 + tid; z < W_ZN; z += 256 * 256) zbase[z] = 0.f;

    if (blk < 64) {
        int T  = blk * 256 + tid;           // 0..16383
        int ct = T >> 8, j = (T >> 6) & 3, l = T & 63;
        int kb = j & 1, isLo = j >> 1;
        int c  = ct * 16 + (l & 15), g = l >> 4;
        half8 o;
        #pragma unroll
        for (int e = 0; e < 8; ++e) {
            int kd = kb * 32 + g * 4 + (e & 3) + ((e >> 2) << 4);
            float wv = w[c * 64 + kd];
            _Float16 h = (fabsf(wv) >= F16_MIN_NORM) ? (_Float16)wv : (_Float16)0.f;
            if (isLo) {
                float hf = (float)h;
                o[e] = (_Float16)((wv - hf) * 16384.0f);   // lo scaled 2^14
            } else {
                o[e] = h;
            }
        }
        *(half8*)(wbf + ((ct * 4 + j) * 64 + l) * 8) = o;
    }

    if (blk < 16) {           // wsq
        int j0 = blk * 64;
        for (int p = 0; p < 16; ++p) {
            int f = p * 256 + tid;
            int j = f >> 6, d = f & 63;
            sh[j][d] = w[(j0 + j) * 64 + d];
        }
        __syncthreads();
        if (tid < 64) {
            double s = 0.0;
            #pragma unroll
            for (int d = 0; d < 64; ++d) {
                double v = (double)sh[tid][d];
                s = fma(v, v, s);
            }
            wsq[j0 + tid] = (float)s;
        }
    }
}

// =====================================================================
// kernel 1 (fused): MFMA distances + argmin + quant/loss/counts/dw.
// MSHR/L1-sharing structure: grid 256 (EXACTLY 1 block/CU) x 512 thr
// (8 waves). Block = 128 rows; wave wid owns row-tile wid (16 rows) and
// walks ALL 64 cts in the same order as every other wave (simultaneous
// same-line loads merge in L1 MSHRs -> per-CU L1 misses drop 1MB->256KB).
// __syncthreads() every 4 cts bounds inter-wave drift far below the
// 32KB L1 window. Each wave produces its rows' final argmin directly
// (all 1024 codes, ct-ascending, strict < -> first-min; no merge).
// Per-(row,ct) numerics bitwise-identical to rounds 10-22.
// =====================================================================
__global__ __launch_bounds__(512, 2)
void k_dist(const float* __restrict__ x, const _Float16* __restrict__ wbf,
            const float* __restrict__ wsq,
            const float* __restrict__ w,
            float* __restrict__ out_idxf,
            float* __restrict__ outq, float* __restrict__ counts,
            float* __restrict__ dw, float* __restrict__ loss) {
    __shared__ _Float16 xhi[64 * 128];      // 16 KB  [kd][row]
    __shared__ _Float16 xlo[64 * 128];      // 16 KB
    __shared__ float x32[128][65];          // 33.3 KB
    __shared__ float q32[128][65];          // 33.3 KB
    __shared__ float rsq[128];
    __shared__ int   idxl[128];
    __shared__ float red[8];
    int tid = threadIdx.x;
    int rbase = blockIdx.x * 128;
    int b = rbase >> 10, hw0 = rbase & 1023;
    const float* xb = x + b * 65536 + hw0;

    // stage 128 rows -> f16 hi/lo (xlo scaled 2^11) + fp32 copy
    #pragma unroll
    for (int p = 0; p < 4; ++p) {
        int f = p * 512 + tid;
        int d = f >> 5, r4 = (f & 31) << 2;
        float4 v = *(const float4*)(xb + d * 1024 + r4);
        float vv[4] = {v.x, v.y, v.z, v.w};
        half4v h, lo;
        #pragma unroll
        for (int q = 0; q < 4; ++q) {
            float xv = vv[q];
            _Float16 hh = (fabsf(xv) >= F16_MIN_NORM) ? (_Float16)xv : (_Float16)0.f;
            h[q]  = hh;
            lo[q] = (_Float16)((xv - (float)hh) * 2048.0f);
            x32[r4 + q][d] = xv;
        }
        *(half4v*)&xhi[d * 128 + r4] = h;
        *(half4v*)&xlo[d * 128 + r4] = lo;
    }
    __syncthreads();

    // in-block rsq: fp64, d ascending (bitwise identical to r21)
    if (tid < 128) {
        double s = 0.0;
        #pragma unroll
        for (int d = 0; d < 64; ++d) {
            double v = (double)x32[tid][d];
            s = fma(v, v, s);
        }
        rsq[tid] = (float)s;
    }

    int l   = tid & 63;
    int wid = tid >> 6;          // row-tile of this wave (0..7)
    int g = l >> 4, n16 = l & 15;
    int row = wid * 16 + n16;

    // A fragments for this wave's row-tile (resident whole loop)
    half8 ahi[2], alo[2];
    #pragma unroll
    for (int kb = 0; kb < 2; ++kb) {
        #pragma unroll
        for (int e = 0; e < 8; ++e) {
            int kd = kb * 32 + g * 4 + (e & 3) + ((e >> 2) << 4);
            ahi[kb][e] = xhi[kd * 128 + row];
            alo[kb][e] = xlo[kd * 128 + row];
        }
    }
    __syncthreads();   // rsq visible; waves aligned entering the loop

    float rq[4];
    #pragma unroll
    for (int i = 0; i < 4; ++i) rq[i] = rsq[wid * 16 + g * 4 + i];

    float best[4];
    int   bidx[4];
    #pragma unroll
    for (int i = 0; i < 4; ++i) { best[i] = 3.4e38f; bidx[i] = 0; }

    const half8* wv8 = (const half8*)wbf;

    // prologue prefetch (ct = 0) — all waves same addresses (MSHR-merged)
    const half8* wp0 = wv8 + l;
    half8 pbh0 = wp0[0], pbh1 = wp0[64], pbl0 = wp0[128], pbl1 = wp0[192];
    float pwsq = wsq[n16];

    #pragma unroll 1
    for (int ct = 0; ct < 64; ++ct) {
        half8 bh0 = pbh0, bh1 = pbh1, bl0 = pbl0, bl1 = pbl1;
        float wsqv = pwsq;
        if (ct < 63) {       // prefetch next ct (wave-uniform branch)
            const half8* wn = wv8 + (ct + 1) * 256 + l;
            pbh0 = wn[0]; pbh1 = wn[64]; pbl0 = wn[128]; pbl1 = wn[192];
            pwsq = wsq[(ct + 1) * 16 + n16];
        }
        int n = ct * 16 + n16;

        f32x4 c1 = {0.f, 0.f, 0.f, 0.f};
        f32x4 c2 = {0.f, 0.f, 0.f, 0.f};
        f32x4 c3 = {0.f, 0.f, 0.f, 0.f};
        c1 = __builtin_amdgcn_mfma_f32_16x16x32_f16(ahi[0], bh0, c1, 0, 0, 0);
        c1 = __builtin_amdgcn_mfma_f32_16x16x32_f16(ahi[1], bh1, c1, 0, 0, 0);
        c2 = __builtin_amdgcn_mfma_f32_16x16x32_f16(alo[0], bh0, c2, 0, 0, 0);
        c2 = __builtin_amdgcn_mfma_f32_16x16x32_f16(alo[1], bh1, c2, 0, 0, 0);
        c3 = __builtin_amdgcn_mfma_f32_16x16x32_f16(ahi[0], bl0, c3, 0, 0, 0);
        c3 = __builtin_amdgcn_mfma_f32_16x16x32_f16(ahi[1], bl1, c3, 0, 0, 0);

        #pragma unroll
        for (int i = 0; i < 4; ++i) {
            float dot = fmaf(c2[i], 4.8828125e-4f, c1[i]);      // +C2*2^-11
            dot = fmaf(c3[i], 6.103515625e-05f, dot);           // +C3*2^-14
            float t1 = rq[i] + wsqv;                            // fl32 add @ ~64
            float sc = fmaf(dot, -2.0f, t1);                    // one rounding
            if (sc < best[i]) { best[i] = sc; bidx[i] = n; }    // ct asc => first-min
        }

        // keep the 8 waves lock-step so they share the L1-resident B chunk
        if ((ct & 3) == 3) __syncthreads();
    }

    // reduce across the 16 lanes of each group (tie -> lower index)
    #pragma unroll
    for (int off = 1; off < 16; off <<= 1) {
        #pragma unroll
        for (int i = 0; i < 4; ++i) {
            float ov = __shfl_xor(best[i], off);
            int   oi = __shfl_xor(bidx[i], off);
            if (ov < best[i] || (ov == best[i] && oi < bidx[i])) {
                best[i] = ov; bidx[i] = oi;
            }
        }
    }
    if (n16 == 0) {
        #pragma unroll
        for (int i = 0; i < 4; ++i) {
            int rl = wid * 16 + g * 4 + i;
            idxl[rl] = bidx[i];
            out_idxf[rbase + rl] = (float)bidx[i];
            atomicAdd(&counts[bidx[i]], 1.0f);
        }
    }
    __syncthreads();

    // ---- fused quant phase (r18-verified 16-rows-per-wave patterns) ----
    #pragma unroll
    for (int v = 0; v < 4; ++v) {
        int n  = wid * 16 + v * 4 + (l >> 4);    // 4 rows per instr
        int d4 = (l & 15) << 2;
        *(float4*)&q32[n][d4] = *(const float4*)(w + idxl[n] * 64 + d4);
    }
    __syncthreads();

    float ll = 0.f;
    #pragma unroll
    for (int p = 0; p < 16; ++p) {
        int e = p * 512 + tid;
        int nn = e & 127, d = e >> 7;
        float q  = q32[nn][d];
        float xv = x32[nn][d];
        float dd = q - xv;
        ll += dd * dd;
        outq[b * 65536 + d * 1024 + hw0 + nn] = q;   // coalesced
    }
    #pragma unroll
    for (int off = 32; off; off >>= 1) ll += __shfl_down(ll, off);
    if (l == 0) red[wid] = ll;
    __syncthreads();
    if (tid == 0) {
        float s = 0.f;
        #pragma unroll
        for (int i = 0; i < 8; ++i) s += red[i];
        atomicAdd(loss, s);
    }

    // dw: lane = d, one coalesced 256B atomic row per vector (16 rows/wave)
    #pragma unroll
    for (int v = 0; v < 16; ++v) {
        int n = wid * 16 + v;
        atomicAdd(&dw[idxl[n] * 64 + l], x32[n][l]);
    }
}

// =====================================================================
// kernel 2 (merged finalize, round-9-verified)
// =====================================================================
__global__ __launch_bounds__(256)
void k_final(const float* __restrict__ ema_cs, const float* __restrict__ ema_w,
             const float* __restrict__ counts, const float* __restrict__ dw,
             const float* __restrict__ loss, float* __restrict__ out) {
    __shared__ float cs[1024];
    __shared__ float redA[4], redB[4];
    int tid = threadIdx.x;

    float necs[4];
    float s1 = 0.f, s2 = 0.f;
    #pragma unroll
    for (int q = 0; q < 4; ++q) {
        int j = q * 256 + tid;
        float c  = counts[j];
        float ne = 0.99f * ema_cs[j] + 0.01f * c;
        necs[q] = ne;
        float p = c * (1.0f / 32768.0f);
        s1 += ne;
        s2 += -p * logf(p + 1e-10f);
    }
    #pragma unroll
    for (int off = 32; off; off >>= 1) {
        s1 += __shfl_down(s1, off);
        s2 += __shfl_down(s2, off);
    }
    if ((tid & 63) == 0) { redA[tid >> 6] = s1; redB[tid >> 6] = s2; }
    __syncthreads();
    float ntot = redA[0] + redA[1] + redA[2] + redA[3];
    #pragma unroll
    for (int q = 0; q < 4; ++q)
        cs[q * 256 + tid] = (necs[q] + 1e-5f) / (ntot + 1024.0f * 1e-5f) * ntot;

    if (blockIdx.x == 0) {
        #pragma unroll
        for (int q = 0; q < 4; ++q) out[O_NECS + q * 256 + tid] = necs[q];
        if (tid == 0) {
            out[O_PERP] = expf(redB[0] + redB[1] + redB[2] + redB[3]);
            out[O_LOSS] = 0.25f * loss[0] * (1.0f / 2097152.0f);
        }
    }
    __syncthreads();

    int f = blockIdx.x * 256 + tid;
    int j = f >> 6;
    float ne = 0.99f * ema_w[f] + 0.01f * dw[f];
    out[O_EMAW + f] = ne;
    out[O_W + f]    = ne / cs[j];
}

// =====================================================================
extern "C" void kernel_launch(void* const* d_in, const int* in_sizes, int n_in,
                              void* d_out, int out_size, void* d_ws, size_t ws_size,
                              hipStream_t stream) {
    const float* x      = (const float*)d_in[0];
    const float* w      = (const float*)d_in[1];
    const float* ema_cs = (const float*)d_in[2];
    const float* ema_w  = (const float*)d_in[3];
    float* out = (float*)d_out;
    float* ws  = (float*)d_ws;

    _Float16* wbf  = (_Float16*)(ws + W_WBF);
    float* wsq     = ws + W_SW2;
    float* counts  = ws + W_CNT;
    float* dwb     = ws + W_DW;
    float* lossb   = ws + W_LOSS;

    k_prep <<<256, 256, 0, stream>>>(w, wbf, wsq, counts);
    k_dist <<<256, 512, 0, stream>>>(x, wbf, wsq, w,
                                     out + O_IDX, out + O_Q, counts, dwb, lossb);
    k_final<<<256, 256, 0, stream>>>(ema_cs, ema_w, counts, dwb, lossb, out);
}

// Round 24
// 43.149 us; speedup vs baseline: 1.3824x; 1.3824x over previous
//
#include <hip/hip_runtime.h>
#include <math.h>

typedef _Float16 half8 __attribute__((ext_vector_type(8)));
typedef _Float16 half4v __attribute__((ext_vector_type(4)));
typedef float    f32x4 __attribute__((ext_vector_type(4)));

// ---------------- output offsets (floats) ----------------
#define O_Q     0
#define O_LOSS  2097152
#define O_IDX   2097153
#define O_PERP  2129921
#define O_NECS  2129922
#define O_EMAW  2130946
#define O_W     2196482

// ---------------- workspace offsets (4-byte units) ----------------
#define W_WBF    0          // 65536 fl (=131072 halfs): B-fragments [64ct][4j][64l][8e]
#define W_SW2    65536      // 1024  wsq  (fl32 of fp64 sum)
#define W_CNT    132096     // 1024  counts
#define W_DW     133120     // 65536 dw
#define W_LOSS   198656     // 1     loss
#define W_ZN     66561      // floats to zero starting at W_CNT

#define F16_MIN_NORM 6.103515625e-05f   // 2^-14

// =====================================================================
// kernel 0 (prep, grid 256): wbf + wsq + zeroing (r21-verified)
// =====================================================================
__global__ __launch_bounds__(256)
void k_prep(const float* __restrict__ w,
            _Float16* __restrict__ wbf, float* __restrict__ wsq,
            float* __restrict__ zbase) {
    __shared__ float sh[64][65];
    int tid = threadIdx.x, blk = blockIdx.x;

    for (int z = blk * 256 + tid; z < W_ZN; z += 256 * 256) zbase[z] = 0.f;

    if (blk < 64) {
        int T  = blk * 256 + tid;           // 0..16383
        int ct = T >> 8, j = (T >> 6) & 3, l = T & 63;
        int kb = j & 1, isLo = j >> 1;
        int c  = ct * 16 + (l & 15), g = l >> 4;
        half8 o;
        #pragma unroll
        for (int e = 0; e < 8; ++e) {
            int kd = kb * 32 + g * 4 + (e & 3) + ((e >> 2) << 4);
            float wv = w[c * 64 + kd];
            _Float16 h = (fabsf(wv) >= F16_MIN_NORM) ? (_Float16)wv : (_Float16)0.f;
            if (isLo) {
                float hf = (float)h;
                o[e] = (_Float16)((wv - hf) * 16384.0f);   // lo scaled 2^14
            } else {
                o[e] = h;
            }
        }
        *(half8*)(wbf + ((ct * 4 + j) * 64 + l) * 8) = o;
    }

    if (blk < 16) {           // wsq
        int j0 = blk * 64;
        for (int p = 0; p < 16; ++p) {
            int f = p * 256 + tid;
            int j = f >> 6, d = f & 63;
            sh[j][d] = w[(j0 + j) * 64 + d];
        }
        __syncthreads();
        if (tid < 64) {
            double s = 0.0;
            #pragma unroll
            for (int d = 0; d < 64; ++d) {
                double v = (double)sh[tid][d];
                s = fma(v, v, s);
            }
            wsq[j0 + tid] = (float)s;
        }
    }
}

// =====================================================================
// kernel 1 (fused): MFMA distances + argmin + quant/loss/counts/dw.
// EXACT r21 structure (best measured total, 43.3 us): grid 1024 x 4
// waves; wave = ct-quarter x 2 row-tiles; depth-1 B/wsq prefetch;
// in-block fp64 rsq from staged x32; coalesced quant gather.
// Per-(row,ct) numerics bitwise-identical to rounds 10-23.
// =====================================================================
__global__ __launch_bounds__(256, 4)
void k_dist(const float* __restrict__ x, const _Float16* __restrict__ wbf,
            const float* __restrict__ wsq,
            const float* __restrict__ w,
            float* __restrict__ out_idxf,
            float* __restrict__ outq, float* __restrict__ counts,
            float* __restrict__ dw, float* __restrict__ loss) {
    __shared__ _Float16 xhi[64 * 32];
    __shared__ _Float16 xlo[64 * 32];
    __shared__ float x32[32][65];
    __shared__ float q32[32][65];
    __shared__ float rsq[32];
    __shared__ float bvs[4][32];
    __shared__ int   bis[4][32];
    __shared__ int   idxl[32];
    __shared__ float red[4];
    int tid = threadIdx.x;
    int rbase = blockIdx.x * 32;
    int b = rbase >> 10, hw0 = rbase & 1023;
    const float* xb = x + b * 65536 + hw0;

    // stage 32 rows -> f16 hi/lo (xlo scaled 2^11) + fp32 copy
    #pragma unroll
    for (int p = 0; p < 2; ++p) {
        int f = p * 256 + tid;
        int d = f >> 3, r4 = (f & 7) << 2;
        float4 v = *(const float4*)(xb + d * 1024 + r4);
        float vv[4] = {v.x, v.y, v.z, v.w};
        half4v h, lo;
        #pragma unroll
        for (int q = 0; q < 4; ++q) {
            float xv = vv[q];
            _Float16 hh = (fabsf(xv) >= F16_MIN_NORM) ? (_Float16)xv : (_Float16)0.f;
            h[q]  = hh;
            lo[q] = (_Float16)((xv - (float)hh) * 2048.0f);
            x32[r4 + q][d] = xv;
        }
        *(half4v*)&xhi[d * 32 + r4] = h;
        *(half4v*)&xlo[d * 32 + r4] = lo;
    }
    __syncthreads();

    // in-block rsq: fp64, d ascending over x32[row][d] — bitwise identical
    // to the former k_prep rsq (same accumulation order, one fl32 rounding)
    if (tid < 32) {
        double s = 0.0;
        #pragma unroll
        for (int d = 0; d < 64; ++d) {
            double v = (double)x32[tid][d];
            s = fma(v, v, s);
        }
        rsq[tid] = (float)s;
    }

    int l   = tid & 63;
    int wid = tid >> 6;          // ct-quarter of this wave
    int g = l >> 4, n16 = l & 15;

    // A fragments for BOTH row-tiles (resident for the whole ct loop)
    half8 ahi[2][2], alo[2][2];
    #pragma unroll
    for (int t = 0; t < 2; ++t)
        #pragma unroll
        for (int kb = 0; kb < 2; ++kb) {
            #pragma unroll
            for (int e = 0; e < 8; ++e) {
                int kd = kb * 32 + g * 4 + (e & 3) + ((e >> 2) << 4);
                ahi[t][kb][e] = xhi[kd * 32 + t * 16 + n16];
                alo[t][kb][e] = xlo[kd * 32 + t * 16 + n16];
            }
        }
    __syncthreads();   // rsq visible to all waves

    float rq[2][4];
    #pragma unroll
    for (int t = 0; t < 2; ++t)
        #pragma unroll
        for (int i = 0; i < 4; ++i)
            rq[t][i] = rsq[t * 16 + g * 4 + i];

    float best[2][4];
    int   bidx[2][4];
    #pragma unroll
    for (int t = 0; t < 2; ++t)
        #pragma unroll
        for (int i = 0; i < 4; ++i) { best[t][i] = 3.4e38f; bidx[t][i] = 0; }

    const half8* wv8 = (const half8*)wbf;

    // prologue prefetch (ct = wid*16)
    const half8* wp0 = wv8 + (wid * 16) * 256 + l;
    half8 pbh0 = wp0[0], pbh1 = wp0[64], pbl0 = wp0[128], pbl1 = wp0[192];
    float pwsq = wsq[(wid * 16) * 16 + n16];

    #pragma unroll 1
    for (int c8 = 0; c8 < 16; ++c8) {
        int ct = wid * 16 + c8;
        half8 bh0 = pbh0, bh1 = pbh1, bl0 = pbl0, bl1 = pbl1;
        float wsqv = pwsq;
        if (c8 < 15) {       // prefetch next ct (wave-uniform branch)
            const half8* wn = wv8 + (ct + 1) * 256 + l;
            pbh0 = wn[0]; pbh1 = wn[64]; pbl0 = wn[128]; pbl1 = wn[192];
            pwsq = wsq[(ct + 1) * 16 + n16];
        }
        int n = ct * 16 + n16;

        #pragma unroll
        for (int t = 0; t < 2; ++t) {
            f32x4 c1 = {0.f, 0.f, 0.f, 0.f};
            f32x4 c2 = {0.f, 0.f, 0.f, 0.f};
            f32x4 c3 = {0.f, 0.f, 0.f, 0.f};
            c1 = __builtin_amdgcn_mfma_f32_16x16x32_f16(ahi[t][0], bh0, c1, 0, 0, 0);
            c1 = __builtin_amdgcn_mfma_f32_16x16x32_f16(ahi[t][1], bh1, c1, 0, 0, 0);
            c2 = __builtin_amdgcn_mfma_f32_16x16x32_f16(alo[t][0], bh0, c2, 0, 0, 0);
            c2 = __builtin_amdgcn_mfma_f32_16x16x32_f16(alo[t][1], bh1, c2, 0, 0, 0);
            c3 = __builtin_amdgcn_mfma_f32_16x16x32_f16(ahi[t][0], bl0, c3, 0, 0, 0);
            c3 = __builtin_amdgcn_mfma_f32_16x16x32_f16(ahi[t][1], bl1, c3, 0, 0, 0);

            #pragma unroll
            for (int i = 0; i < 4; ++i) {
                float dot = fmaf(c2[i], 4.8828125e-4f, c1[i]);      // +C2*2^-11
                dot = fmaf(c3[i], 6.103515625e-05f, dot);           // +C3*2^-14
                float t1 = rq[t][i] + wsqv;                         // fl32 add @ ~64
                float sc = fmaf(dot, -2.0f, t1);                    // one rounding
                if (sc < best[t][i]) { best[t][i] = sc; bidx[t][i] = n; }
            }
        }
    }

    // reduce across the 16 lanes of each group (tie -> lower index)
    #pragma unroll
    for (int off = 1; off < 16; off <<= 1) {
        #pragma unroll
        for (int t = 0; t < 2; ++t)
            #pragma unroll
            for (int i = 0; i < 4; ++i) {
                float ov = __shfl_xor(best[t][i], off);
                int   oi = __shfl_xor(bidx[t][i], off);
                if (ov < best[t][i] || (ov == best[t][i] && oi < bidx[t][i])) {
                    best[t][i] = ov; bidx[t][i] = oi;
                }
            }
    }
    if (n16 == 0) {
        #pragma unroll
        for (int t = 0; t < 2; ++t)
            #pragma unroll
            for (int i = 0; i < 4; ++i) {
                bvs[wid][t * 16 + g * 4 + i] = best[t][i];
                bis[wid][t * 16 + g * 4 + i] = bidx[t][i];
            }
    }
    __syncthreads();

    // merge ct-quarters (wid ascending = ct ascending -> first-min)
    if (tid < 32) {
        float bb = bvs[0][tid]; int ii = bis[0][tid];
        #pragma unroll
        for (int q = 1; q < 4; ++q) {
            float ov = bvs[q][tid]; int oi = bis[q][tid];
            if (ov < bb) { bb = ov; ii = oi; }
        }
        idxl[tid] = ii;
        out_idxf[rbase + tid] = (float)ii;
        atomicAdd(&counts[ii], 1.0f);
    }
    __syncthreads();

    // ---- fused quant phase (r14-verified patterns) ----
    #pragma unroll
    for (int v = 0; v < 2; ++v) {
        int n  = wid * 8 + v * 4 + (l >> 4);     // 4 rows per instr
        int d4 = (l & 15) << 2;
        *(float4*)&q32[n][d4] = *(const float4*)(w + idxl[n] * 64 + d4);
    }
    __syncthreads();

    float ll = 0.f;
    #pragma unroll
    for (int p = 0; p < 8; ++p) {
        int e = p * 256 + tid;
        int nn = e & 31, d = e >> 5;
        float q  = q32[nn][d];
        float xv = x32[nn][d];
        float dd = q - xv;
        ll += dd * dd;
        outq[b * 65536 + d * 1024 + hw0 + nn] = q;   // coalesced
    }
    #pragma unroll
    for (int off = 32; off; off >>= 1) ll += __shfl_down(ll, off);
    if (l == 0) red[wid] = ll;
    __syncthreads();
    if (tid == 0) atomicAdd(loss, red[0] + red[1] + red[2] + red[3]);

    // dw: lane = d, one coalesced 256B atomic row per vector
    #pragma unroll
    for (int v = 0; v < 8; ++v) {
        int n = wid * 8 + v;
        atomicAdd(&dw[idxl[n] * 64 + l], x32[n][l]);
    }
}

// =====================================================================
// kernel 2 (merged finalize, round-9-verified)
// =====================================================================
__global__ __launch_bounds__(256)
void k_final(const float* __restrict__ ema_cs, const float* __restrict__ ema_w,
             const float* __restrict__ counts, const float* __restrict__ dw,
             const float* __restrict__ loss, float* __restrict__ out) {
    __shared__ float cs[1024];
    __shared__ float redA[4], redB[4];
    int tid = threadIdx.x;

    float necs[4];
    float s1 = 0.f, s2 = 0.f;
    #pragma unroll
    for (int q = 0; q < 4; ++q) {
        int j = q * 256 + tid;
        float c  = counts[j];
        float ne = 0.99f * ema_cs[j] + 0.01f * c;
        necs[q] = ne;
        float p = c * (1.0f / 32768.0f);
        s1 += ne;
        s2 += -p * logf(p + 1e-10f);
    }
    #pragma unroll
    for (int off = 32; off; off >>= 1) {
        s1 += __shfl_down(s1, off);
        s2 += __shfl_down(s2, off);
    }
    if ((tid & 63) == 0) { redA[tid >> 6] = s1; redB[tid >> 6] = s2; }
    __syncthreads();
    float ntot = redA[0] + redA[1] + redA[2] + redA[3];
    #pragma unroll
    for (int q = 0; q < 4; ++q)
        cs[q * 256 + tid] = (necs[q] + 1e-5f) / (ntot + 1024.0f * 1e-5f) * ntot;

    if (blockIdx.x == 0) {
        #pragma unroll
        for (int q = 0; q < 4; ++q) out[O_NECS + q * 256 + tid] = necs[q];
        if (tid == 0) {
            out[O_PERP] = expf(redB[0] + redB[1] + redB[2] + redB[3]);
            out[O_LOSS] = 0.25f * loss[0] * (1.0f / 2097152.0f);
        }
    }
    __syncthreads();

    int f = blockIdx.x * 256 + tid;
    int j = f >> 6;
    float ne = 0.99f * ema_w[f] + 0.01f * dw[f];
    out[O_EMAW + f] = ne;
    out[O_W + f]    = ne / cs[j];
}

// =====================================================================
extern "C" void kernel_launch(void* const* d_in, const int* in_sizes, int n_in,
                              void* d_out, int out_size, void* d_ws, size_t ws_size,
                              hipStream_t stream) {
    const float* x      = (const float*)d_in[0];
    const float* w      = (const float*)d_in[1];
    const float* ema_cs = (const float*)d_in[2];
    const float* ema_w  = (const float*)d_in[3];
    float* out = (float*)d_out;
    float* ws  = (float*)d_ws;

    _Float16* wbf  = (_Float16*)(ws + W_WBF);
    float* wsq     = ws + W_SW2;
    float* counts  = ws + W_CNT;
    float* dwb     = ws + W_DW;
    float* lossb   = ws + W_LOSS;

    k_prep <<<256,  256, 0, stream>>>(w, wbf, wsq, counts);
    k_dist <<<1024, 256, 0, stream>>>(x, wbf, wsq, w,
                                      out + O_IDX, out + O_Q, counts, dwb, lossb);
    k_final<<<256,  256, 0, stream>>>(ema_cs, ema_w, counts, dwb, lossb, out);
}